// Round 8
// baseline (8827.547 us; speedup 1.0000x reference)
//
#include <hip/hip_runtime.h>
#include <hip/hip_bf16.h>
#include <stdint.h>

#define SEQ_T 4096
#define EMB   300
#define HID   512
#define G4    2048
#define NTAG  12
#define TAG_START 10
#define TAG_STOP  11
#define NEGV  -10000.0f
#define NCHUNK 256
#define CLEN   16

// ---- workspace layout (float offsets) ----
#define OFF_XG    0                               // 2 * 4096 * 2048
#define OFF_H     (OFF_XG + 2 * SEQ_T * G4)       // uint64[2 parity][2 dir][512] = 4096 floats
#define OFF_HS    (OFF_H + 4096)                  // 2 * 4096 * 512
#define OFF_FEATS (OFF_HS + 2 * SEQ_T * HID)      // 4096 * 12
#define OFF_VM    (OFF_FEATS + SEQ_T * NTAG)      // 256 chunk matrices: 256*144
#define OFF_VB    (OFF_VM + NCHUNK * 144)         // 256 boundary fv: 256*12
#define OFF_VSC   (OFF_VB + NCHUNK * NTAG)        // [0]=best tag (int); pad 8
#define OFF_VP    (OFF_VSC + 8)                   // path packs: 256*12 u64
#define OFF_VMAP  (OFF_VP + NCHUNK * NTAG * 2)    // chunk maps: 256 u64
#define WS_FLOATS (OFF_VMAP + NCHUNK * 2)

__device__ __forceinline__ float sigm_(float x) {
    return __fdividef(1.f, 1.f + __expf(-x));
}
__device__ __forceinline__ float tanh_(float x) {
    x = fminf(fmaxf(x, -15.f), 15.f);
    float e = __expf(2.f * x);
    return __fdividef(e - 1.f, e + 1.f);
}

// ---- embedding gather + input projection as an LDS-tiled GEMM ----
__global__ __launch_bounds__(256) void k_xg(const int* __restrict__ sent,
                                            const float* __restrict__ table,
                                            const float* __restrict__ Wih_f,
                                            const float* __restrict__ bih_f,
                                            const float* __restrict__ bhh_f,
                                            const float* __restrict__ Wih_b,
                                            const float* __restrict__ bih_b,
                                            const float* __restrict__ bhh_b,
                                            float* __restrict__ ws) {
    __shared__ float As[64 * 105];
    __shared__ float Bs[64 * 105];
    __shared__ int rows[64];
    const int dir = blockIdx.z;
    const int g0  = blockIdx.x << 6;
    const int t0  = blockIdx.y << 6;
    const int tid = threadIdx.x;
    const float* __restrict__ Wih = dir ? Wih_b : Wih_f;
    const float* __restrict__ bih = dir ? bih_b : bih_f;
    const float* __restrict__ bhh = dir ? bhh_b : bhh_f;
    if (tid < 64) rows[tid] = sent[t0 + tid];
    __syncthreads();

    const int tg = (tid & 15) << 2;
    const int tp = (tid >> 4) << 2;
    float acc[4][4] = {{0.f}};

    for (int c = 0; c < 3; ++c) {
        const int k0 = c * 100;
        for (int e = tid; e < 64 * 100; e += 256) {
            int ti = e / 100, kk = e - ti * 100;
            As[ti * 105 + kk] = table[(size_t)rows[ti] * EMB + k0 + kk];
        }
        for (int e = tid; e < 64 * 100; e += 256) {
            int gi = e / 100, kk = e - gi * 100;
            Bs[gi * 105 + kk] = Wih[(size_t)(g0 + gi) * EMB + k0 + kk];
        }
        __syncthreads();
        for (int kk = 0; kk < 100; ++kk) {
            float a0 = As[(tp + 0) * 105 + kk];
            float a1 = As[(tp + 1) * 105 + kk];
            float a2 = As[(tp + 2) * 105 + kk];
            float a3 = As[(tp + 3) * 105 + kk];
            float b0 = Bs[(tg + 0) * 105 + kk];
            float b1 = Bs[(tg + 1) * 105 + kk];
            float b2 = Bs[(tg + 2) * 105 + kk];
            float b3 = Bs[(tg + 3) * 105 + kk];
            acc[0][0] = fmaf(a0, b0, acc[0][0]); acc[0][1] = fmaf(a0, b1, acc[0][1]);
            acc[0][2] = fmaf(a0, b2, acc[0][2]); acc[0][3] = fmaf(a0, b3, acc[0][3]);
            acc[1][0] = fmaf(a1, b0, acc[1][0]); acc[1][1] = fmaf(a1, b1, acc[1][1]);
            acc[1][2] = fmaf(a1, b2, acc[1][2]); acc[1][3] = fmaf(a1, b3, acc[1][3]);
            acc[2][0] = fmaf(a2, b0, acc[2][0]); acc[2][1] = fmaf(a2, b1, acc[2][1]);
            acc[2][2] = fmaf(a2, b2, acc[2][2]); acc[2][3] = fmaf(a2, b3, acc[2][3]);
            acc[3][0] = fmaf(a3, b0, acc[3][0]); acc[3][1] = fmaf(a3, b1, acc[3][1]);
            acc[3][2] = fmaf(a3, b2, acc[3][2]); acc[3][3] = fmaf(a3, b3, acc[3][3]);
        }
        __syncthreads();
    }
    float4 bv4 = *(const float4*)(bih + g0 + tg);
    float4 bh4 = *(const float4*)(bhh + g0 + tg);
    float4 bb = make_float4(bv4.x + bh4.x, bv4.y + bh4.y, bv4.z + bh4.z, bv4.w + bh4.w);
    #pragma unroll
    for (int i = 0; i < 4; ++i) {
        float4 r = make_float4(acc[i][0] + bb.x, acc[i][1] + bb.y,
                               acc[i][2] + bb.z, acc[i][3] + bb.w);
        *(float4*)(ws + OFF_XG + ((size_t)dir * SEQ_T + t0 + tp + i) * G4 + g0 + tg) = r;
    }
}

// ---- persistent bidirectional LSTM scan ----
// Round-5 proven structure. Change: only WAVE 0 of each block polls the
// packed (epoch<<32|h_bits) IC slots (8 stride-64 u64 loads per lane,
// selective retry) and stages to LDS -> 8x fewer IC line-requests per step;
// waves 1-7 go straight to the barrier. Transitive-barrier safety unchanged
// (wave 0 still reads ALL 512 slots every step before its block advances).
__global__ __launch_bounds__(512, 2) void k_scan(const float* __restrict__ Whh_f,
                                                 const float* __restrict__ Whh_b,
                                                 float* __restrict__ ws) {
    __shared__ float h_sh[2][8 * 68];   // [parity][seg*68 + idx]
    const int bid = blockIdx.x;
    const int tid = threadIdx.x;
    const int dir = bid >> 5;
    const int wg  = bid & 31;
    const int wave = tid >> 6;
    const int lane = tid & 63;
    const int s  = lane >> 4;
    const int qq = (lane >> 3) & 1;
    const int p  = lane & 7;
    const int hu   = (wg << 4) + (wave << 1) + qq;
    const int gate = (s << 9) + hu;
    const float* __restrict__ Whh = dir ? Whh_b : Whh_f;

    float* xg = ws + OFF_XG + (size_t)dir * SEQ_T * G4;
    unsigned long long* hbuf = (unsigned long long*)(ws + OFF_H);
    float* hs = ws + OFF_HS + (size_t)dir * SEQ_T * HID;

    float4 w[16];
    {
        const float4* wrow = (const float4*)(Whh + (size_t)gate * HID + (p << 6));
        #pragma unroll
        for (int j = 0; j < 16; ++j) w[j] = wrow[j];
    }

    const bool owner = (s == 0) && (p == 0);
    float c = 0.f;
    float xg_cur = 0.f;
    if (p == 0) xg_cur = xg[(size_t)(dir ? (SEQ_T - 1) : 0) * G4 + gate];

    for (int k = 0; k < SEQ_T; ++k) {
        const int time = dir ? (SEQ_T - 1 - k) : k;
        float xg_nxt = 0.f;
        if (p == 0 && (k + 1) < SEQ_T)
            xg_nxt = xg[(size_t)(dir ? (time - 1) : (time + 1)) * G4 + gate];

        float acc = xg_cur;
        if (k > 0) {
            const int par = (k - 1) & 1;
            if (wave == 0) {   // wave 0 polls all 512 slots: 8 stride-64 u64/lane
                const unsigned want = (unsigned)(k - 1);
                unsigned long long* src = hbuf + ((size_t)(par << 1) + dir) * HID;
                unsigned long long v[8];
                unsigned pend = 0xFFu;
                do {
                    #pragma unroll
                    for (int j = 0; j < 8; ++j)
                        if (pend & (1u << j))
                            v[j] = __hip_atomic_load(src + (j << 6) + lane,
                                                     __ATOMIC_RELAXED,
                                                     __HIP_MEMORY_SCOPE_AGENT);
                    #pragma unroll
                    for (int j = 0; j < 8; ++j)
                        if ((pend & (1u << j)) && (unsigned)(v[j] >> 32) == want) {
                            h_sh[par][j * 68 + lane] = __uint_as_float((unsigned)v[j]);
                            pend &= ~(1u << j);
                        }
                } while (pend);
            }
            __syncthreads();   // staged h visible to all 8 waves
            const float4* hp = (const float4*)(&h_sh[par][p * 68]);
            float ax = 0.f, ay = 0.f, az = 0.f, aw = 0.f;
            #pragma unroll
            for (int j = 0; j < 16; ++j) {
                float4 hv = hp[j];
                ax = fmaf(w[j].x, hv.x, ax);
                ay = fmaf(w[j].y, hv.y, ay);
                az = fmaf(w[j].z, hv.z, az);
                aw = fmaf(w[j].w, hv.w, aw);
            }
            acc += (ax + ay) + (az + aw);
        }
        // 8-way partial reduction over the p dimension (lane bits 0..2)
        acc += __shfl_xor(acc, 1);
        acc += __shfl_xor(acc, 2);
        acc += __shfl_xor(acc, 4);
        // distributed nonlinearity: each lane applies its gate's activation
        float nl = (s == 2) ? tanh_(acc) : sigm_(acc);
        const int base = lane & 15;
        float gi = __shfl(nl, base + 0);
        float gf = __shfl(nl, base + 16);
        float gt = __shfl(nl, base + 32);
        float go = __shfl(nl, base + 48);
        if (owner) {
            c = fmaf(gf, c, gi * gt);
            float h = go * tanh_(c);
            hs[(size_t)time * HID + hu] = h;               // persistent output
            unsigned long long pv = ((unsigned long long)(unsigned)k << 32) |
                                    (unsigned long long)__float_as_uint(h);
            __hip_atomic_store(&hbuf[((size_t)((k & 1) << 1) + dir) * HID + hu], pv,
                               __ATOMIC_RELAXED, __HIP_MEMORY_SCOPE_AGENT);
        }
        xg_cur = xg_nxt;
        // no trailing barrier: next step stages into the other h_sh parity
    }
}

// ---- output projection: feats[t][tag] = [h_f, h_b] @ W_out^T + b_out ----
__global__ __launch_bounds__(256) void k_feats(const float* __restrict__ Wout,
                                               const float* __restrict__ bout,
                                               float* __restrict__ ws) {
    const int t = blockIdx.x;
    const int tid = threadIdx.x;
    const float* hsf = ws + OFF_HS;
    const float* hsb = ws + OFF_HS + (size_t)SEQ_T * HID;
    float4 h4 = (tid < 128) ? ((const float4*)(hsf + (size_t)t * HID))[tid]
                            : ((const float4*)(hsb + (size_t)t * HID))[tid - 128];
    float pj[NTAG];
    #pragma unroll
    for (int j = 0; j < NTAG; ++j) {
        float4 wv = ((const float4*)(Wout + (size_t)j * 2 * HID))[tid];
        pj[j] = h4.x * wv.x + h4.y * wv.y + h4.z * wv.z + h4.w * wv.w;
    }
    #pragma unroll
    for (int j = 0; j < NTAG; ++j) {
        #pragma unroll
        for (int m = 1; m < 64; m <<= 1) pj[j] += __shfl_xor(pj[j], m);
    }
    __shared__ float red[4][NTAG];
    if ((tid & 63) == 0) {
        #pragma unroll
        for (int j = 0; j < NTAG; ++j) red[tid >> 6][j] = pj[j];
    }
    __syncthreads();
    if (tid < NTAG) {
        float v = red[0][tid] + red[1][tid] + red[2][tid] + red[3][tid] + bout[tid];
        ws[OFF_FEATS + (size_t)t * NTAG + tid] = v;
    }
}

// ---- Viterbi stage A: per-chunk max-plus products of 16 step matrices ----
__global__ __launch_bounds__(192) void k_vitA(const float* __restrict__ trans,
                                              float* __restrict__ ws) {
    __shared__ float M[NTAG][13];
    __shared__ float T[NTAG][NTAG];
    const int c = blockIdx.x;
    const int tid = threadIdx.x;
    const float* feats = ws + OFF_FEATS;
    const int j = tid / NTAG, i = tid - j * NTAG;
    if (tid < 144) T[j][i] = trans[tid];
    __syncthreads();
    float cur = 0.f;
    const int t0 = c * CLEN;
    if (tid < 144) cur = T[j][i] + feats[(size_t)t0 * NTAG + j];
    for (int t = t0 + 1; t < t0 + CLEN; ++t) {
        if (tid < 144) M[j][i] = cur;
        __syncthreads();
        if (tid < 144) {
            float fj = feats[(size_t)t * NTAG + j];
            float best = -3.4e38f;
            #pragma unroll
            for (int kk = 0; kk < NTAG; ++kk)
                best = fmaxf(best, T[j][kk] + M[kk][i]);
            cur = best + fj;
        }
        __syncthreads();
    }
    if (tid < 144) ws[OFF_VM + (size_t)c * 144 + tid] = cur;
}

// ---- Viterbi stage B: sequential combine of chunk matrices ----
__global__ __launch_bounds__(192) void k_vitB(const float* __restrict__ trans,
                                              float* __restrict__ ws,
                                              float* __restrict__ out) {
    __shared__ float Ms[NTAG][13];
    __shared__ float fvs[NTAG];
    const int tid = threadIdx.x;
    const int j = tid / NTAG, i = tid - j * NTAG;
    if (tid < NTAG) fvs[tid] = (tid == TAG_START) ? 0.f : NEGV;
    float m = (tid < 144) ? ws[OFF_VM + tid] : 0.f;
    for (int c = 0; c < NCHUNK; ++c) {
        if (tid < 144) Ms[j][i] = m;
        __syncthreads();
        if (tid < 144 && (c + 1) < NCHUNK)
            m = ws[OFF_VM + (size_t)(c + 1) * 144 + tid];
        float nf = 0.f;
        if (tid < NTAG) {
            ws[OFF_VB + (size_t)c * NTAG + tid] = fvs[tid];
            float best = -3.4e38f;
            #pragma unroll
            for (int kk = 0; kk < NTAG; ++kk)
                best = fmaxf(best, Ms[tid][kk] + fvs[kk]);
            nf = best;
        }
        __syncthreads();
        if (tid < NTAG) fvs[tid] = nf;
        __syncthreads();
    }
    if (tid == 0) {
        float bsc = -3.4e38f; int btag = 0;
        for (int q = 0; q < NTAG; ++q) {
            float tv = fvs[q] + trans[TAG_STOP * NTAG + q];
            if (q == TAG_START || q == TAG_STOP) tv = NEGV;
            if (tv > bsc) { bsc = tv; btag = q; }
        }
        out[0] = bsc;
        ((int*)(ws + OFF_VSC))[0] = btag;
    }
}

// ---- Viterbi stage C: per-chunk backpointers + hypothetical backtracks ----
__global__ __launch_bounds__(256) void k_vitC(const float* __restrict__ trans,
                                              float* __restrict__ ws) {
    const int lane = threadIdx.x & 63;
    const int c = blockIdx.x * 4 + (threadIdx.x >> 6);
    const float* feats = ws + OFF_FEATS;
    float Trow[NTAG];
    #pragma unroll
    for (int i = 0; i < NTAG; ++i)
        Trow[i] = (lane < NTAG) ? trans[lane * NTAG + i] : -1e30f;
    float fv = (lane < NTAG) ? ws[OFF_VB + (size_t)c * NTAG + lane] : NEGV;

    unsigned bpLo[CLEN], bpHi[CLEN];
    const int t0 = c * CLEN;
    #pragma unroll
    for (int tt = 0; tt < CLEN; ++tt) {
        const int t = t0 + tt;
        float vv[NTAG];
        #pragma unroll
        for (int i = 0; i < NTAG; ++i) vv[i] = __shfl(fv, i) + Trow[i];
        float m0; int i0;
        {
            float a0 = vv[0];  int b0 = 0;  if (vv[1]  > a0) { a0 = vv[1];  b0 = 1; }
            float a1 = vv[2];  int b1 = 2;  if (vv[3]  > a1) { a1 = vv[3];  b1 = 3; }
            float a2 = vv[4];  int b2 = 4;  if (vv[5]  > a2) { a2 = vv[5];  b2 = 5; }
            float a3 = vv[6];  int b3 = 6;  if (vv[7]  > a3) { a3 = vv[7];  b3 = 7; }
            float a4 = vv[8];  int b4 = 8;  if (vv[9]  > a4) { a4 = vv[9];  b4 = 9; }
            float a5 = vv[10]; int b5 = 10; if (vv[11] > a5) { a5 = vv[11]; b5 = 11; }
            if (a1 > a0) { a0 = a1; b0 = b1; }
            if (a3 > a2) { a2 = a3; b2 = b3; }
            if (a5 > a4) { a4 = a5; b4 = b5; }
            if (a2 > a0) { a0 = a2; b0 = b2; }
            if (a4 > a0) { a0 = a4; b0 = b4; }
            m0 = a0; i0 = b0;
        }
        fv = (lane < NTAG) ? (m0 + feats[(size_t)t * NTAG + lane]) : NEGV;
        unsigned nib = (lane < NTAG) ? ((unsigned)i0 << ((lane & 7) << 2)) : 0u;
        nib |= __shfl_xor(nib, 1);
        nib |= __shfl_xor(nib, 2);
        nib |= __shfl_xor(nib, 4);
        bpLo[tt] = __shfl(nib, 0);
        bpHi[tt] = __shfl(nib, 8);
    }
    if (lane < NTAG) {
        int tag = lane;
        unsigned long long pk = 0ull;
        #pragma unroll
        for (int tt = CLEN - 1; tt >= 0; --tt) {
            pk |= ((unsigned long long)(unsigned)tag) << (tt << 2);
            unsigned wsel = (tag < 8) ? bpLo[tt] : bpHi[tt];
            tag = (int)((wsel >> ((tag & 7) << 2)) & 15u);
        }
        ((unsigned long long*)(ws + OFF_VP))[(size_t)c * NTAG + lane] = pk;
        unsigned long long mc = ((unsigned long long)(unsigned)tag) << (lane << 2);
        mc |= __shfl_xor(mc, 1);
        mc |= __shfl_xor(mc, 2);
        mc |= __shfl_xor(mc, 4);
        mc |= __shfl_xor(mc, 8);
        if (lane == 0) ((unsigned long long*)(ws + OFF_VMAP))[c] = mc;
    }
}

// ---- Viterbi stage D: chain chunk maps backward, emit path ----
__global__ __launch_bounds__(64) void k_vitD(float* __restrict__ ws,
                                             float* __restrict__ out) {
    const int lane = threadIdx.x;
    const unsigned long long* vp = (const unsigned long long*)(ws + OFF_VP);
    const unsigned long long* vmap = (const unsigned long long*)(ws + OFF_VMAP);
    int tag = ((const int*)(ws + OFF_VSC))[0];
    for (int c = NCHUNK - 1; c >= 0; --c) {
        unsigned long long row = (lane < NTAG) ? vp[(size_t)c * NTAG + lane] : 0ull;
        unsigned long long mp = vmap[c];
        unsigned long long pk = __shfl(row, tag);
        if (lane < CLEN)
            out[c * CLEN + lane + 1] = (float)((pk >> (lane << 2)) & 15ull);
        tag = (int)((mp >> (tag << 2)) & 15ull);
    }
}

extern "C" void kernel_launch(void* const* d_in, const int* in_sizes, int n_in,
                              void* d_out, int out_size, void* d_ws, size_t ws_size,
                              hipStream_t stream) {
    const int*   sent  = (const int*)d_in[0];
    const float* table = (const float*)d_in[1];
    const float* Wih_f = (const float*)d_in[2];
    const float* Whh_f = (const float*)d_in[3];
    const float* bih_f = (const float*)d_in[4];
    const float* bhh_f = (const float*)d_in[5];
    const float* Wih_b = (const float*)d_in[6];
    const float* Whh_b = (const float*)d_in[7];
    const float* bih_b = (const float*)d_in[8];
    const float* bhh_b = (const float*)d_in[9];
    const float* Wout  = (const float*)d_in[10];
    const float* bout  = (const float*)d_in[11];
    const float* trans = (const float*)d_in[12];
    float* out = (float*)d_out;
    float* ws  = (float*)d_ws;
    if (ws_size < (size_t)WS_FLOATS * sizeof(float)) return;

    hipLaunchKernelGGL(k_xg, dim3(32, 64, 2), dim3(256), 0, stream, sent, table,
                       Wih_f, bih_f, bhh_f, Wih_b, bih_b, bhh_b, ws);
    hipLaunchKernelGGL(k_scan, dim3(64), dim3(512), 0, stream, Whh_f, Whh_b, ws);
    hipLaunchKernelGGL(k_feats, dim3(SEQ_T), dim3(256), 0, stream, Wout, bout, ws);
    hipLaunchKernelGGL(k_vitA, dim3(NCHUNK), dim3(192), 0, stream, trans, ws);
    hipLaunchKernelGGL(k_vitB, dim3(1), dim3(192), 0, stream, trans, ws, out);
    hipLaunchKernelGGL(k_vitC, dim3(NCHUNK / 4), dim3(256), 0, stream, trans, ws);
    hipLaunchKernelGGL(k_vitD, dim3(1), dim3(64), 0, stream, ws, out);
}